// Round 1
// baseline (242.905 us; speedup 1.0000x reference)
//
#include <hip/hip_runtime.h>

// Problem constants (match reference)
constexpr int N = 20000;   // vertices
constexpr int T = 32;      // temporal depth
constexpr int E = 640000;  // edges
constexpr int C = 10;      // conv out channels
constexpr int K = 5;       // conv kernel size
constexpr int PAD = 2;     // 'same' padding

// ---------------------------------------------------------------------------
// 1) in-degree histogram (mean-aggregation denominator)
__global__ void k_degree(const int* __restrict__ dst, float* __restrict__ cnt) {
    int e = blockIdx.x * 256 + threadIdx.x;
    if (e < E) atomicAdd(&cnt[dst[e]], 1.0f);
}

// cnt -> 1/max(cnt,1)
__global__ void k_recip(float* __restrict__ cnt) {
    int n = blockIdx.x * 256 + threadIdx.x;
    if (n < N) cnt[n] = 1.0f / fmaxf(cnt[n], 1.0f);
}

// ---------------------------------------------------------------------------
// 2) per-column sums: stats[0..31]=sum(x), stats[32..63]=sum(x^2)
__global__ __launch_bounds__(256) void k_stats(const float* __restrict__ x,
                                               float* __restrict__ stats) {
    int tid = threadIdx.x;
    int t = tid & 31;                       // column of every element this thread touches
    float sx = 0.f, sx2 = 0.f;
    for (int i = blockIdx.x * blockDim.x + tid; i < N * T; i += gridDim.x * blockDim.x) {
        float v = x[i];
        sx += v; sx2 += v * v;
    }
    // fold the two 32-lane halves of the wave (same column)
    sx  += __shfl_xor(sx, 32);
    sx2 += __shfl_xor(sx2, 32);
    __shared__ float sS[2][T];
    if (tid < T) { sS[0][tid] = 0.f; sS[1][tid] = 0.f; }
    __syncthreads();
    if ((tid & 63) < 32) {                  // one lane per column per wave
        atomicAdd(&sS[0][t], sx);
        atomicAdd(&sS[1][t], sx2);
    }
    __syncthreads();
    if (tid < T) {
        atomicAdd(&stats[tid],     sS[0][tid]);
        atomicAdd(&stats[T + tid], sS[1][tid]);
    }
}

// ---------------------------------------------------------------------------
// 3) per-node: GraphNorm affine + Conv1d(1->C,'same') + max over channels.
//    8 rows per 256-thread block, row tile in LDS with halo.
__global__ __launch_bounds__(256) void k_node(
    const float* __restrict__ x, const float* __restrict__ stats,
    const float* __restrict__ W, const float* __restrict__ b,
    const float* __restrict__ alpha, const float* __restrict__ scale,
    const float* __restrict__ shift,
    float* __restrict__ xhat, float* __restrict__ msg) {
    __shared__ float tile[8][T + 2 * PAD];
    __shared__ float sW[C * K], sb[C];
    int tid = threadIdx.x;
    if (tid < C * K) sW[tid] = W[tid];
    if (tid < C)     sb[tid] = b[tid];
    int r = tid >> 5, t = tid & 31;
    int row = blockIdx.x * 8 + r;

    // column affine coefficients (recomputed redundantly per thread, cheap)
    float Sx = stats[t], Sx2 = stats[T + t];
    float mu   = Sx * (1.0f / (float)N);
    float am   = alpha[t] * mu;
    float nrm2 = Sx2 - 2.f * am * Sx + (float)N * am * am;
    float g    = scale[t] * sqrtf((float)N) * rsqrtf(nrm2);
    float h    = shift[t] - am * g;

    float v = g * x[row * T + t] + h;
    xhat[row * T + t] = v;
    if (t < PAD) { tile[r][t] = 0.f; tile[r][T + PAD + t] = 0.f; }
    tile[r][t + PAD] = v;
    __syncthreads();

    float m = -1e30f;
#pragma unroll
    for (int c = 0; c < C; ++c) {
        float acc = sb[c];
#pragma unroll
        for (int k = 0; k < K; ++k)
            acc += sW[c * K + k] * tile[r][t + k];
        m = fmaxf(m, acc);
    }
    msg[row * T + t] = m;
}

// ---------------------------------------------------------------------------
// 4) edge scatter: one thread per (edge, t). 32 consecutive threads share an
//    edge -> coalesced msg row read, atomics into aggr[dst] row.
__global__ __launch_bounds__(256) void k_scatter(
    const int* __restrict__ src, const int* __restrict__ dst,
    const float* __restrict__ msg, float* __restrict__ aggr) {
    long long g = (long long)blockIdx.x * 256 + threadIdx.x;
    int e = (int)(g >> 5);
    if (e < E) {
        int t = (int)(g & 31);
        int s = src[e], d = dst[e];
        atomicAdd(&aggr[d * T + t], msg[s * T + t]);
    }
}

// ---------------------------------------------------------------------------
// 5) update: x_new = relu(0.5*(xhat + aggr/denom))
__global__ __launch_bounds__(256) void k_update(
    const float* __restrict__ xhat, const float* __restrict__ aggr,
    const float* __restrict__ rcp, float* __restrict__ xnew) {
    int i = blockIdx.x * 256 + threadIdx.x;
    if (i < N * T) {
        int n = i >> 5;
        float v = 0.5f * (xhat[i] + aggr[i] * rcp[n]);
        xnew[i] = fmaxf(v, 0.f);
    }
}

// ---------------------------------------------------------------------------
// 6) output: out[j] = bout[j] + sum_n Wout[j,n] * sum_t x[n,t]
__global__ void k_out_init(const float* __restrict__ bout, float* __restrict__ out) {
    int i = threadIdx.x;
    if (i < 3) out[i] = bout[i];
}

__global__ __launch_bounds__(256) void k_final(
    const float* __restrict__ x, const float* __restrict__ Wout,
    float* __restrict__ out) {
    int tid = blockIdx.x * blockDim.x + threadIdx.x;
    float a0 = 0.f, a1 = 0.f, a2 = 0.f;
    for (int n = tid; n < N; n += gridDim.x * blockDim.x) {
        const float* row = x + n * T;
        float s = 0.f;
#pragma unroll
        for (int t = 0; t < T; ++t) s += row[t];
        a0 += Wout[n] * s;
        a1 += Wout[N + n] * s;
        a2 += Wout[2 * N + n] * s;
    }
#pragma unroll
    for (int off = 32; off; off >>= 1) {
        a0 += __shfl_down(a0, off);
        a1 += __shfl_down(a1, off);
        a2 += __shfl_down(a2, off);
    }
    if ((threadIdx.x & 63) == 0) {
        atomicAdd(&out[0], a0);
        atomicAdd(&out[1], a1);
        atomicAdd(&out[2], a2);
    }
}

// ---------------------------------------------------------------------------
extern "C" void kernel_launch(void* const* d_in, const int* in_sizes, int n_in,
                              void* d_out, int out_size, void* d_ws, size_t ws_size,
                              hipStream_t stream) {
    const float* x_in  = (const float*)d_in[0];
    const float* convW = (const float*)d_in[1];
    const float* convb = (const float*)d_in[2];
    const float* alpha = (const float*)d_in[3];
    const float* scale = (const float*)d_in[4];
    const float* shift = (const float*)d_in[5];
    const float* Wout  = (const float*)d_in[6];
    const float* bout  = (const float*)d_in[7];
    const int*   ei    = (const int*)d_in[8];
    const int* src = ei;          // edge_index[0]
    const int* dst = ei + E;      // edge_index[1]

    float* ws    = (float*)d_ws;
    float* rcp   = ws;                    // N
    float* stats = ws + N;                // 64
    float* xcur  = stats + 2 * T;         // N*T
    float* xhat  = xcur + N * T;          // N*T
    float* msgb  = xhat + N * T;          // N*T
    float* aggr  = msgb + N * T;          // N*T

    float* out = (float*)d_out;

    // degree -> reciprocal
    hipMemsetAsync(rcp, 0, N * sizeof(float), stream);
    k_degree<<<(E + 255) / 256, 256, 0, stream>>>(dst, rcp);
    k_recip<<<(N + 255) / 256, 256, 0, stream>>>(rcp);

    for (int l = 0; l < 2; ++l) {
        const float* xin = (l == 0) ? x_in : xcur;
        hipMemsetAsync(stats, 0, 2 * T * sizeof(float), stream);
        k_stats<<<120, 256, 0, stream>>>(xin, stats);
        hipMemsetAsync(aggr, 0, (size_t)N * T * sizeof(float), stream);
        k_node<<<N / 8, 256, 0, stream>>>(xin, stats,
                                          convW + l * C * K, convb + l * C,
                                          alpha + l * T, scale + l * T, shift + l * T,
                                          xhat, msgb);
        k_scatter<<<(int)(((long long)E * 32 + 255) / 256), 256, 0, stream>>>(src, dst, msgb, aggr);
        k_update<<<(N * T + 255) / 256, 256, 0, stream>>>(xhat, aggr, rcp, xcur);
    }

    k_out_init<<<1, 64, 0, stream>>>(bout, out);
    k_final<<<40, 256, 0, stream>>>(xcur, Wout, out);
}

// Round 2
// 216.316 us; speedup vs baseline: 1.1229x; 1.1229x over previous
//
#include <hip/hip_runtime.h>

// Problem constants (match reference)
constexpr int N = 20000;   // vertices
constexpr int T = 32;      // temporal depth
constexpr int E = 640000;  // edges
constexpr int C = 10;      // conv out channels
constexpr int K = 5;       // conv kernel size
constexpr int PAD = 2;     // 'same' padding

// ---------------------------------------------------------------------------
// 1) in-degree histogram (int)
__global__ void k_degree(const int* __restrict__ dst, int* __restrict__ deg) {
    int e = blockIdx.x * 256 + threadIdx.x;
    if (e < E) atomicAdd(&deg[dst[e]], 1);
}

// ---------------------------------------------------------------------------
// 2) single-block exclusive scan: deg -> off[0..N]; also cursor[n] = off[n].
//    deg and cursor may alias (each thread reads its chunk before writing it).
__global__ __launch_bounds__(1024) void k_scan(const int* __restrict__ deg,
                                               int* __restrict__ off,
                                               int* __restrict__ cursor) {
    __shared__ int part[1024];
    constexpr int CH = (N + 1023) / 1024;   // 20
    int tid = threadIdx.x;
    int base = tid * CH;
    int loc[CH];
    int s = 0;
#pragma unroll
    for (int k = 0; k < CH; ++k) {
        int n = base + k;
        int d = (n < N) ? deg[n] : 0;
        loc[k] = s;
        s += d;
    }
    part[tid] = s;
    __syncthreads();
    for (int ofs = 1; ofs < 1024; ofs <<= 1) {
        int v = (tid >= ofs) ? part[tid - ofs] : 0;
        __syncthreads();
        part[tid] += v;
        __syncthreads();
    }
    int pre = (tid == 0) ? 0 : part[tid - 1];
#pragma unroll
    for (int k = 0; k < CH; ++k) {
        int n = base + k;
        if (n < N) { int o = pre + loc[k]; off[n] = o; cursor[n] = o; }
    }
    if (tid == 1023) off[N] = part[1023];
}

// ---------------------------------------------------------------------------
// 3) bin edges into CSR: csr[pos] = src, grouped by dst
__global__ void k_bin(const int* __restrict__ src, const int* __restrict__ dst,
                      int* __restrict__ cursor, int* __restrict__ csr) {
    int e = blockIdx.x * 256 + threadIdx.x;
    if (e < E) {
        int p = atomicAdd(&cursor[dst[e]], 1);
        csr[p] = src[e];
    }
}

// ---------------------------------------------------------------------------
// 4) per-column sums: stats[0..31]=sum(x), stats[32..63]=sum(x^2)
__global__ __launch_bounds__(256) void k_stats(const float* __restrict__ x,
                                               float* __restrict__ stats) {
    int tid = threadIdx.x;
    int t = tid & 31;
    float sx = 0.f, sx2 = 0.f;
    for (int i = blockIdx.x * blockDim.x + tid; i < N * T; i += gridDim.x * blockDim.x) {
        float v = x[i];
        sx += v; sx2 += v * v;
    }
    sx  += __shfl_xor(sx, 32);
    sx2 += __shfl_xor(sx2, 32);
    __shared__ float sS[2][T];
    if (tid < T) { sS[0][tid] = 0.f; sS[1][tid] = 0.f; }
    __syncthreads();
    if ((tid & 63) < 32) {
        atomicAdd(&sS[0][t], sx);
        atomicAdd(&sS[1][t], sx2);
    }
    __syncthreads();
    if (tid < T) {
        atomicAdd(&stats[tid],     sS[0][tid]);
        atomicAdd(&stats[T + tid], sS[1][tid]);
    }
}

// ---------------------------------------------------------------------------
// 5) per-node: GraphNorm affine + Conv1d(1->C,'same') + max over channels
__global__ __launch_bounds__(256) void k_node(
    const float* __restrict__ x, const float* __restrict__ stats,
    const float* __restrict__ W, const float* __restrict__ b,
    const float* __restrict__ alpha, const float* __restrict__ scale,
    const float* __restrict__ shift,
    float* __restrict__ xhat, float* __restrict__ msg) {
    __shared__ float tile[8][T + 2 * PAD];
    __shared__ float sW[C * K], sb[C];
    int tid = threadIdx.x;
    if (tid < C * K) sW[tid] = W[tid];
    if (tid < C)     sb[tid] = b[tid];
    int r = tid >> 5, t = tid & 31;
    int row = blockIdx.x * 8 + r;

    float Sx = stats[t], Sx2 = stats[T + t];
    float mu   = Sx * (1.0f / (float)N);
    float am   = alpha[t] * mu;
    float nrm2 = Sx2 - 2.f * am * Sx + (float)N * am * am;
    float g    = scale[t] * sqrtf((float)N) * rsqrtf(nrm2);
    float h    = shift[t] - am * g;

    float v = g * x[row * T + t] + h;
    xhat[row * T + t] = v;
    if (t < PAD) { tile[r][t] = 0.f; tile[r][T + PAD + t] = 0.f; }
    tile[r][t + PAD] = v;
    __syncthreads();

    float m = -1e30f;
#pragma unroll
    for (int c = 0; c < C; ++c) {
        float acc = sb[c];
#pragma unroll
        for (int k = 0; k < K; ++k)
            acc += sW[c * K + k] * tile[r][t + k];
        m = fmaxf(m, acc);
    }
    msg[row * T + t] = m;
}

// ---------------------------------------------------------------------------
// 6) fused gather-aggregate (mean) + update + ReLU. One wave per node.
//    lane = eo*32 + t: two edges in flight per iteration, rows coalesced.
__global__ __launch_bounds__(256) void k_gather(
    const int* __restrict__ off, const int* __restrict__ csr,
    const float* __restrict__ msg, const float* __restrict__ xhat,
    float* __restrict__ xnew) {
    int wid = (blockIdx.x * 256 + threadIdx.x) >> 6;   // wave id == node id
    if (wid >= N) return;
    int lane = threadIdx.x & 63;
    int t = lane & 31, eo = lane >> 5;
    int o0 = off[wid], o1 = off[wid + 1];
    int deg = o1 - o0;
    float acc = 0.f;
    for (int i = eo; i < deg; i += 2) {
        int s = csr[o0 + i];
        acc += msg[s * T + t];
    }
    acc += __shfl_xor(acc, 32);
    if (eo == 0) {
        float r = 1.0f / fmaxf((float)deg, 1.0f);
        float v = 0.5f * (xhat[wid * T + t] + acc * r);
        xnew[wid * T + t] = fmaxf(v, 0.f);
    }
}

// ---------------------------------------------------------------------------
// 7) output: out[j] = bout[j] + sum_n Wout[j,n] * sum_t x[n,t]
__global__ void k_out_init(const float* __restrict__ bout, float* __restrict__ out) {
    int i = threadIdx.x;
    if (i < 3) out[i] = bout[i];
}

__global__ __launch_bounds__(256) void k_final(
    const float* __restrict__ x, const float* __restrict__ Wout,
    float* __restrict__ out) {
    int tid = blockIdx.x * blockDim.x + threadIdx.x;
    float a0 = 0.f, a1 = 0.f, a2 = 0.f;
    for (int n = tid; n < N; n += gridDim.x * blockDim.x) {
        const float* row = x + n * T;
        float s = 0.f;
#pragma unroll
        for (int t = 0; t < T; ++t) s += row[t];
        a0 += Wout[n] * s;
        a1 += Wout[N + n] * s;
        a2 += Wout[2 * N + n] * s;
    }
#pragma unroll
    for (int off = 32; off; off >>= 1) {
        a0 += __shfl_down(a0, off);
        a1 += __shfl_down(a1, off);
        a2 += __shfl_down(a2, off);
    }
    if ((threadIdx.x & 63) == 0) {
        atomicAdd(&out[0], a0);
        atomicAdd(&out[1], a1);
        atomicAdd(&out[2], a2);
    }
}

// ---------------------------------------------------------------------------
extern "C" void kernel_launch(void* const* d_in, const int* in_sizes, int n_in,
                              void* d_out, int out_size, void* d_ws, size_t ws_size,
                              hipStream_t stream) {
    const float* x_in  = (const float*)d_in[0];
    const float* convW = (const float*)d_in[1];
    const float* convb = (const float*)d_in[2];
    const float* alpha = (const float*)d_in[3];
    const float* scale = (const float*)d_in[4];
    const float* shift = (const float*)d_in[5];
    const float* Wout  = (const float*)d_in[6];
    const float* bout  = (const float*)d_in[7];
    const int*   ei    = (const int*)d_in[8];
    const int* src = ei;          // edge_index[0]
    const int* dst = ei + E;      // edge_index[1]

    // workspace layout
    int*   ioff  = (int*)d_ws;            // N+1
    int*   icur  = ioff + (N + 1);        // N   (deg during histogram, cursor after scan)
    int*   icsr  = icur + N;              // E
    float* stats = (float*)(icsr + E);    // 64
    float* xcur  = stats + 2 * T;         // N*T
    float* xhat  = xcur + N * T;          // N*T
    float* msgb  = xhat + N * T;          // N*T

    float* out = (float*)d_out;

    // CSR build (once per call; reused across both layers)
    hipMemsetAsync(icur, 0, N * sizeof(int), stream);
    k_degree<<<(E + 255) / 256, 256, 0, stream>>>(dst, icur);
    k_scan<<<1, 1024, 0, stream>>>(icur, ioff, icur);
    k_bin<<<(E + 255) / 256, 256, 0, stream>>>(src, dst, icur, icsr);

    for (int l = 0; l < 2; ++l) {
        const float* xin = (l == 0) ? x_in : xcur;
        hipMemsetAsync(stats, 0, 2 * T * sizeof(float), stream);
        k_stats<<<120, 256, 0, stream>>>(xin, stats);
        k_node<<<N / 8, 256, 0, stream>>>(xin, stats,
                                          convW + l * C * K, convb + l * C,
                                          alpha + l * T, scale + l * T, shift + l * T,
                                          xhat, msgb);
        k_gather<<<(N * 64 + 255) / 256, 256, 0, stream>>>(ioff, icsr, msgb, xhat, xcur);
    }

    k_out_init<<<1, 64, 0, stream>>>(bout, out);
    k_final<<<40, 256, 0, stream>>>(xcur, Wout, out);
}